// Round 1
// baseline (182.185 us; speedup 1.0000x reference)
//
#include <hip/hip_runtime.h>

// Problem: B=2, S=2048, D=512, H=8, dh=64.
// Pipeline:
//   u[h][d]   = Wh (Wh^T Wv)            (tiny)
//   Q = X @ Wq  (fp32) + Qh (bf16 copy for MFMA)
//   n[b,h,s]  = ||Q_head||, y[b,h,s] = X[b,s,:] . u[h]
//   N[b,h]    = max_s n
//   out       = sigmoid( softmax((2QQ^T - n_s - n_t)/8) @ y )   via MFMA dots

typedef __attribute__((ext_vector_type(8))) short bf16x8;
typedef __attribute__((ext_vector_type(4))) float f32x4;

#if __has_builtin(__builtin_amdgcn_exp2f)
#define EXP2F(x) __builtin_amdgcn_exp2f(x)
#else
#define EXP2F(x) exp2f(x)
#endif

#define LOG2E 1.44269504088896341f

__device__ inline unsigned int f2b(float f) {  // fp32 -> bf16 bits, RNE
    unsigned int u = __float_as_uint(f);
    return (u + 0x7fffu + ((u >> 16) & 1u)) >> 16;
}

// ---- u precompute: t[h][k] = sum_d Wq[d][h*64+k] * Wv[d] ----
__global__ __launch_bounds__(256) void u1_k(const float* __restrict__ Wq,
                                            const float* __restrict__ Wv,
                                            float* __restrict__ t_out) {
    int h = blockIdx.x;                 // 8 blocks
    int tid = threadIdx.x;
    int rr = tid >> 6, c = tid & 63;
    float acc = 0.f;
    for (int j = 0; j < 128; ++j) {
        int d = rr + 4 * j;
        acc = fmaf(Wq[d * 512 + h * 64 + c], Wv[d], acc);
    }
    __shared__ float part[4][64];
    part[rr][c] = acc;
    __syncthreads();
    if (rr == 0) t_out[h * 64 + c] = part[0][c] + part[1][c] + part[2][c] + part[3][c];
}

// ---- u[h][d] = sum_k Wq[d][h*64+k] * t[h][k] ----
__global__ __launch_bounds__(256) void u2_k(const float* __restrict__ Wq,
                                            const float* __restrict__ t_in,
                                            float* __restrict__ u_out) {
    int idx = blockIdx.x * 256 + threadIdx.x;   // 16 blocks -> 4096 = h*512+d
    int h = idx >> 9, d = idx & 511;
    float acc = 0.f;
    #pragma unroll 8
    for (int k = 0; k < 64; ++k)
        acc = fmaf(Wq[d * 512 + h * 64 + k], t_in[h * 64 + k], acc);
    u_out[idx] = acc;
}

// ---- Q = X @ Wq : M=4096, N=512, K=512, fp32, 64x64 tile, 4x4/thread ----
__global__ __launch_bounds__(256) void gemm_q(const float* __restrict__ X,
                                              const float* __restrict__ Wq,
                                              float* __restrict__ Q,
                                              unsigned short* __restrict__ Qh) {
    __shared__ float As[16][68];   // [kk][m], +4 pad
    __shared__ float Bs[16][68];   // [kk][n]
    int tid = threadIdx.x;
    int tx = tid & 15, ty = tid >> 4;
    int m0 = blockIdx.y * 64, n0 = blockIdx.x * 64;
    int lr = tid >> 2, lk4 = (tid & 3) * 4;    // A staging
    int bk = tid >> 4, bn4 = (tid & 15) * 4;   // B staging
    float acc[4][4] = {};
    for (int k0 = 0; k0 < 512; k0 += 16) {
        __syncthreads();
        float4 xa = *(const float4*)&X[(m0 + lr) * 512 + k0 + lk4];
        float4 wb = *(const float4*)&Wq[(k0 + bk) * 512 + n0 + bn4];
        As[lk4 + 0][lr] = xa.x; As[lk4 + 1][lr] = xa.y;
        As[lk4 + 2][lr] = xa.z; As[lk4 + 3][lr] = xa.w;
        *(float4*)&Bs[bk][bn4] = wb;
        __syncthreads();
        #pragma unroll
        for (int kk = 0; kk < 16; ++kk) {
            float4 av = *(const float4*)&As[kk][ty * 4];
            float4 bv = *(const float4*)&Bs[kk][tx * 4];
            float ar[4] = {av.x, av.y, av.z, av.w};
            float br[4] = {bv.x, bv.y, bv.z, bv.w};
            #pragma unroll
            for (int i = 0; i < 4; ++i)
                #pragma unroll
                for (int j = 0; j < 4; ++j)
                    acc[i][j] = fmaf(ar[i], br[j], acc[i][j]);
        }
    }
    #pragma unroll
    for (int i = 0; i < 4; ++i) {
        int row = m0 + ty * 4 + i;
        float4 v; v.x = acc[i][0]; v.y = acc[i][1]; v.z = acc[i][2]; v.w = acc[i][3];
        *(float4*)&Q[row * 512 + n0 + tx * 4] = v;
        unsigned int lo = f2b(acc[i][0]) | (f2b(acc[i][1]) << 16);
        unsigned int hi = f2b(acc[i][2]) | (f2b(acc[i][3]) << 16);
        uint2 hv; hv.x = lo; hv.y = hi;
        *(uint2*)&Qh[row * 512 + n0 + tx * 4] = hv;
    }
}

// ---- per (b,s): head norms n and y = X . u[h] ----
__global__ __launch_bounds__(64) void ny_k(const float* __restrict__ X,
                                           const float* __restrict__ Q,
                                           const float* __restrict__ u,
                                           float* __restrict__ n_out,
                                           float* __restrict__ y_out) {
    int m = blockIdx.x;            // b*S + s
    int lane = threadIdx.x;        // 0..63
    int b = m >> 11, s = m & 2047;
    const float* xr = X + m * 512;
    const float* qr = Q + m * 512;
    float xv[8];
    #pragma unroll
    for (int j = 0; j < 8; ++j) xv[j] = xr[j * 64 + lane];
    float ss[8], ya[8];
    #pragma unroll
    for (int h = 0; h < 8; ++h) {
        float q = qr[h * 64 + lane];
        ss[h] = q * q;
        float a = 0.f;
        #pragma unroll
        for (int j = 0; j < 8; ++j)
            a = fmaf(xv[j], u[h * 512 + j * 64 + lane], a);
        ya[h] = a;
    }
    #pragma unroll
    for (int off = 32; off >= 1; off >>= 1) {
        #pragma unroll
        for (int h = 0; h < 8; ++h) {
            ss[h] += __shfl_xor(ss[h], off);
            ya[h] += __shfl_xor(ya[h], off);
        }
    }
    if (lane == 0) {
        #pragma unroll
        for (int h = 0; h < 8; ++h) {
            int idx = ((b * 8 + h) << 11) + s;
            n_out[idx] = sqrtf(ss[h]);
            y_out[idx] = ya[h];
        }
    }
}

// ---- N[b,h] = max_s n ----
__global__ __launch_bounds__(256) void nmax_k(const float* __restrict__ n_in,
                                              float* __restrict__ nmax) {
    int bh = blockIdx.x;
    int tid = threadIdx.x;
    float mx = 0.f;
    for (int i = tid; i < 2048; i += 256) mx = fmaxf(mx, n_in[bh * 2048 + i]);
    __shared__ float red[256];
    red[tid] = mx;
    __syncthreads();
    for (int o = 128; o >= 1; o >>= 1) {
        if (tid < o) red[tid] = fmaxf(red[tid], red[tid + o]);
        __syncthreads();
    }
    if (tid == 0) nmax[bh] = red[0];
}

// ---- attention: 32 query rows/block, loop t in chunks of 32, MFMA dots ----
// scores = (2*dots - n_s - n_t)/8 ; softmax ; out = sigmoid(sum P*y)
// exp(score - M_s) via exp2: arg = 0.25*LOG2E*dots + rowc[s] + tq[t]
//   rowc = -0.125*LOG2E*N*(2*n_s - 1)  (folds in M_s = (2 n_s N - n_s - N)/8)
//   tq   = -0.125*LOG2E*n_t
__global__ __launch_bounds__(256) void attn_k(const unsigned short* __restrict__ Qh,
                                              const float* __restrict__ n_in,
                                              const float* __restrict__ y_in,
                                              const float* __restrict__ nmax,
                                              float* __restrict__ out) {
    __shared__ __align__(16) unsigned short QsL[32 * 72];  // pad 64->72 bf16/row
    __shared__ __align__(16) unsigned short QtL[32 * 72];
    __shared__ float rowc[32];
    __shared__ float tqL[32], ytL[32];
    __shared__ float redN[2][32], redD[2][32];

    int tid = threadIdx.x;
    int bh = blockIdx.x >> 6;          // b*8+h
    int tile = blockIdx.x & 63;
    int s0 = tile * 32;
    int b = bh >> 3, h = bh & 7;
    int rowbase = (b * 2048) * 512 + h * 64;

    int r = tid >> 3, seg = tid & 7;   // staging: 32 rows x 8 segs of 16B
    *(uint4*)&QsL[r * 72 + seg * 8] =
        *(const uint4*)&Qh[rowbase + (s0 + r) * 512 + seg * 8];
    float Nv = nmax[bh];
    if (tid < 32) {
        float ns = n_in[bh * 2048 + s0 + tid];
        rowc[tid] = -0.125f * LOG2E * Nv * (2.f * ns - 1.f);
    }
    __syncthreads();

    int lane = tid & 63;
    int w = tid >> 6;
    int rh = w >> 1;                   // row-half of 16
    int ch = (w & 1) * 16;             // col-half of 16
    int tt = lane & 15, quad = lane >> 4;
    int arow = rh * 16 + tt;
    bf16x8 a0 = *(const bf16x8*)&QsL[arow * 72 + quad * 8];
    bf16x8 a1 = *(const bf16x8*)&QsL[arow * 72 + quad * 8 + 32];
    float rc[4];
    #pragma unroll
    for (int g = 0; g < 4; ++g) rc[g] = rowc[rh * 16 + quad * 4 + g];
    f32x4 num = {0.f, 0.f, 0.f, 0.f}, den = {0.f, 0.f, 0.f, 0.f};

    for (int t0 = 0; t0 < 2048; t0 += 32) {
        __syncthreads();
        *(uint4*)&QtL[r * 72 + seg * 8] =
            *(const uint4*)&Qh[rowbase + (t0 + r) * 512 + seg * 8];
        if (tid >= 64 && tid < 96)
            tqL[tid - 64] = -0.125f * LOG2E * n_in[bh * 2048 + t0 + tid - 64];
        else if (tid >= 96 && tid < 128)
            ytL[tid - 96] = y_in[bh * 2048 + t0 + tid - 96];
        __syncthreads();

        bf16x8 b0 = *(const bf16x8*)&QtL[(ch + tt) * 72 + quad * 8];
        bf16x8 b1 = *(const bf16x8*)&QtL[(ch + tt) * 72 + quad * 8 + 32];
        f32x4 dot = {0.f, 0.f, 0.f, 0.f};
        dot = __builtin_amdgcn_mfma_f32_16x16x32_bf16(a0, b0, dot, 0, 0, 0);
        dot = __builtin_amdgcn_mfma_f32_16x16x32_bf16(a1, b1, dot, 0, 0, 0);

        float tqv = tqL[ch + tt], yv = ytL[ch + tt];
        #pragma unroll
        for (int g = 0; g < 4; ++g) {
            float arg = fmaf(0.25f * LOG2E, dot[g], rc[g] + tqv);
            float e = EXP2F(arg);
            num[g] = fmaf(e, yv, num[g]);
            den[g] += e;
        }
    }

    // reduce across the 16 lanes of each quad group (cols of the C tile)
    #pragma unroll
    for (int off = 1; off <= 8; off <<= 1) {
        #pragma unroll
        for (int g = 0; g < 4; ++g) {
            num[g] += __shfl_xor(num[g], off);
            den[g] += __shfl_xor(den[g], off);
        }
    }
    if (tt == 0) {
        #pragma unroll
        for (int g = 0; g < 4; ++g) {
            redN[w & 1][rh * 16 + quad * 4 + g] = num[g];
            redD[w & 1][rh * 16 + quad * 4 + g] = den[g];
        }
    }
    __syncthreads();
    if (tid < 32) {
        float xn = redN[0][tid] + redN[1][tid];
        float xd = redD[0][tid] + redD[1][tid];
        float x = xn / xd;
        out[bh * 2048 + s0 + tid] = 1.0f / (1.0f + EXP2F(-x * LOG2E));
    }
}

extern "C" void kernel_launch(void* const* d_in, const int* in_sizes, int n_in,
                              void* d_out, int out_size, void* d_ws, size_t ws_size,
                              hipStream_t stream) {
    const float* X  = (const float*)d_in[0];
    const float* Wq = (const float*)d_in[1];
    const float* Wv = (const float*)d_in[2];
    float* out = (float*)d_out;
    float* ws = (float*)d_ws;

    float* t_ws    = ws;                 // 512
    float* u_ws    = ws + 512;           // 4096
    float* n_ws    = ws + 4608;          // 32768
    float* y_ws    = ws + 37376;         // 32768
    float* nmax_ws = ws + 70144;         // 16
    float* Q_ws    = ws + 70160;         // 2097152 (16B aligned)
    unsigned short* Qh_ws = (unsigned short*)(Q_ws + 2097152);  // 2097152 bf16

    u1_k<<<8, 256, 0, stream>>>(Wq, Wv, t_ws);
    u2_k<<<16, 256, 0, stream>>>(Wq, t_ws, u_ws);
    gemm_q<<<dim3(8, 64), 256, 0, stream>>>(X, Wq, Q_ws, Qh_ws);
    ny_k<<<4096, 64, 0, stream>>>(X, Q_ws, u_ws, n_ws, y_ws);
    nmax_k<<<16, 256, 0, stream>>>(n_ws, nmax_ws);
    attn_k<<<1024, 256, 0, stream>>>(Qh_ws, n_ws, y_ws, nmax_ws, out);
}

// Round 2
// 122.600 us; speedup vs baseline: 1.4860x; 1.4860x over previous
//
#include <hip/hip_runtime.h>

// Problem: B=2, S=2048, D=512, H=8, dh=64.
// Pipeline (all-bf16 MFMA for the heavy matmuls):
//   prep: Xh=bf16(X), Wqt=bf16(Wq^T), t[h]=Wh^T Wv
//   u2:   u[h] = Wh t[h]
//   gemm: Qh = Xh @ Wq  (bf16 MFMA, 64x64 tile)
//   ny:   n[b,h,s]=||Q_head||, y[b,h,s]=X[b,s,:].u[h] ; nmax: N[b,h]=max n
//   attn: out = sigmoid( softmax((2QQ^T - n_s - n_t)/8) @ y )
//         exact upper bound M_s = (2 n_s N - n_s - N)/8 -> no online rescale

typedef __attribute__((ext_vector_type(8))) short bf16x8;
typedef __attribute__((ext_vector_type(4))) float f32x4;

#if __has_builtin(__builtin_amdgcn_exp2f)
#define EXP2F(x) __builtin_amdgcn_exp2f(x)
#else
#define EXP2F(x) exp2f(x)
#endif

#define LOG2E 1.44269504088896341f

__device__ inline unsigned int f2b(float f) {  // fp32 -> bf16 bits, RNE
    unsigned int u = __float_as_uint(f);
    return (u + 0x7fffu + ((u >> 16) & 1u)) >> 16;
}
__device__ inline float b2f(unsigned short b) {
    return __uint_as_float(((unsigned int)b) << 16);
}

// ---- prep: blocks [0,1024) castX, [1024,1280) transpose-cast Wq, [1280,1288) u1 ----
__global__ __launch_bounds__(256) void prep_k(const float* __restrict__ X,
                                              const float* __restrict__ Wq,
                                              const float* __restrict__ Wv,
                                              unsigned short* __restrict__ Xh,
                                              unsigned short* __restrict__ Wqt,
                                              float* __restrict__ t_out) {
    __shared__ float sh[32 * 33];
    int blk = blockIdx.x;
    int tid = threadIdx.x;
    if (blk < 1024) {
        // cast X -> bf16, 8 elements/thread
        int base = (blk * 256 + tid) * 8;
        float4 a = *(const float4*)&X[base];
        float4 c = *(const float4*)&X[base + 4];
        uint4 o;
        o.x = f2b(a.x) | (f2b(a.y) << 16);
        o.y = f2b(a.z) | (f2b(a.w) << 16);
        o.z = f2b(c.x) | (f2b(c.y) << 16);
        o.w = f2b(c.z) | (f2b(c.w) << 16);
        *(uint4*)&Xh[base] = o;
    } else if (blk < 1280) {
        // transpose-cast Wq (512x512): Wqt[n][k] = Wq[k][n], 32x32 tiles
        int bidx = blk - 1024;
        int k0 = (bidx >> 4) * 32, n0 = (bidx & 15) * 32;
        int r = tid >> 3, c4 = (tid & 7) * 4;
        float4 v = *(const float4*)&Wq[(k0 + r) * 512 + n0 + c4];
        sh[(c4 + 0) * 33 + r] = v.x;
        sh[(c4 + 1) * 33 + r] = v.y;
        sh[(c4 + 2) * 33 + r] = v.z;
        sh[(c4 + 3) * 33 + r] = v.w;
        __syncthreads();
        float w0 = sh[r * 33 + c4 + 0], w1 = sh[r * 33 + c4 + 1];
        float w2 = sh[r * 33 + c4 + 2], w3 = sh[r * 33 + c4 + 3];
        uint2 o;
        o.x = f2b(w0) | (f2b(w1) << 16);
        o.y = f2b(w2) | (f2b(w3) << 16);
        *(uint2*)&Wqt[(n0 + r) * 512 + k0 + c4] = o;
    } else {
        // t[h][k] = sum_d Wq[d][h*64+k] * Wv[d]
        int h = blk - 1280;
        int rr = tid >> 6, c = tid & 63;
        float acc = 0.f;
        for (int j = 0; j < 128; ++j) {
            int d = rr + 4 * j;
            acc = fmaf(Wq[d * 512 + h * 64 + c], Wv[d], acc);
        }
        sh[rr * 64 + c] = acc;
        __syncthreads();
        if (rr == 0)
            t_out[h * 64 + c] = sh[c] + sh[64 + c] + sh[128 + c] + sh[192 + c];
    }
}

// ---- u[h][d] = sum_k Wq[d][h*64+k] * t[h][k] ----
__global__ __launch_bounds__(256) void u2_k(const float* __restrict__ Wq,
                                            const float* __restrict__ t_in,
                                            float* __restrict__ u_out) {
    int idx = blockIdx.x * 256 + threadIdx.x;
    int h = idx >> 9, d = idx & 511;
    float acc = 0.f;
    #pragma unroll 8
    for (int k = 0; k < 64; ++k)
        acc = fmaf(Wq[d * 512 + h * 64 + k], t_in[h * 64 + k], acc);
    u_out[idx] = acc;
}

// ---- Qh = Xh @ Wq via MFMA: M=4096,N=512,K=512; BM=BN=BK=64 ----
__global__ __launch_bounds__(256) void gemm_k(const unsigned short* __restrict__ Xh,
                                              const unsigned short* __restrict__ Wqt,
                                              unsigned short* __restrict__ Qh) {
    __shared__ __align__(16) unsigned short As[64 * 72];
    __shared__ __align__(16) unsigned short Bs[64 * 72];
    int tid = threadIdx.x;
    int m0 = blockIdx.y * 64, n0 = blockIdx.x * 64;
    int w = tid >> 6, lane = tid & 63;
    int tt = lane & 15, quad = lane >> 4;
    int r = tid >> 3, seg = tid & 7;
    int arow = w * 16 + tt;
    f32x4 acc[4] = {{0.f,0.f,0.f,0.f},{0.f,0.f,0.f,0.f},{0.f,0.f,0.f,0.f},{0.f,0.f,0.f,0.f}};
    for (int k0 = 0; k0 < 512; k0 += 64) {
        __syncthreads();
        #pragma unroll
        for (int q = 0; q < 2; ++q) {
            int row = r + q * 32;
            *(uint4*)&As[row * 72 + seg * 8] =
                *(const uint4*)&Xh[(m0 + row) * 512 + k0 + seg * 8];
            *(uint4*)&Bs[row * 72 + seg * 8] =
                *(const uint4*)&Wqt[(n0 + row) * 512 + k0 + seg * 8];
        }
        __syncthreads();
        #pragma unroll
        for (int ks = 0; ks < 2; ++ks) {
            bf16x8 a = *(const bf16x8*)&As[arow * 72 + ks * 32 + quad * 8];
            #pragma unroll
            for (int ct = 0; ct < 4; ++ct) {
                bf16x8 b = *(const bf16x8*)&Bs[(ct * 16 + tt) * 72 + ks * 32 + quad * 8];
                acc[ct] = __builtin_amdgcn_mfma_f32_16x16x32_bf16(a, b, acc[ct], 0, 0, 0);
            }
        }
    }
    #pragma unroll
    for (int ct = 0; ct < 4; ++ct)
        #pragma unroll
        for (int g = 0; g < 4; ++g) {
            int row = m0 + w * 16 + quad * 4 + g;
            int col = n0 + ct * 16 + tt;
            Qh[row * 512 + col] = (unsigned short)f2b(acc[ct][g]);
        }
}

// ---- per (b,s): head norms n (from bf16 Q) and y = X . u[h] ----
__global__ __launch_bounds__(256) void ny_k(const float* __restrict__ X,
                                            const unsigned short* __restrict__ Qh,
                                            const float* __restrict__ u,
                                            float* __restrict__ n_out,
                                            float* __restrict__ y_out) {
    int m = blockIdx.x * 4 + (threadIdx.x >> 6);
    int lane = threadIdx.x & 63;
    int b = m >> 11, s = m & 2047;
    const float* xr = X + m * 512;
    const unsigned short* qr = Qh + m * 512;
    float xv[8];
    #pragma unroll
    for (int j = 0; j < 8; ++j) xv[j] = xr[j * 64 + lane];
    float ss[8], ya[8];
    #pragma unroll
    for (int h = 0; h < 8; ++h) {
        float q = b2f(qr[h * 64 + lane]);
        ss[h] = q * q;
        float a = 0.f;
        #pragma unroll
        for (int j = 0; j < 8; ++j)
            a = fmaf(xv[j], u[h * 512 + j * 64 + lane], a);
        ya[h] = a;
    }
    #pragma unroll
    for (int off = 32; off >= 1; off >>= 1) {
        #pragma unroll
        for (int h = 0; h < 8; ++h) {
            ss[h] += __shfl_xor(ss[h], off);
            ya[h] += __shfl_xor(ya[h], off);
        }
    }
    if (lane == 0) {
        #pragma unroll
        for (int h = 0; h < 8; ++h) {
            int idx = ((b * 8 + h) << 11) + s;
            n_out[idx] = sqrtf(ss[h]);
            y_out[idx] = ya[h];
        }
    }
}

// ---- N[b,h] = max_s n ----
__global__ __launch_bounds__(256) void nmax_k(const float* __restrict__ n_in,
                                              float* __restrict__ nmax) {
    int bh = blockIdx.x;
    int tid = threadIdx.x;
    float mx = 0.f;
    for (int i = tid; i < 2048; i += 256) mx = fmaxf(mx, n_in[bh * 2048 + i]);
    __shared__ float red[256];
    red[tid] = mx;
    __syncthreads();
    for (int o = 128; o >= 1; o >>= 1) {
        if (tid < o) red[tid] = fmaxf(red[tid], red[tid + o]);
        __syncthreads();
    }
    if (tid == 0) nmax[bh] = red[0];
}

// ---- attention: 32 query rows/block, t-chunks of 128, MFMA dots ----
// arg = 0.25*LOG2E*dots + rowc[s] + tq[t];  rowc = -0.125*LOG2E*N*(2 n_s - 1)
__global__ __launch_bounds__(256) void attn_k(const unsigned short* __restrict__ Qh,
                                              const float* __restrict__ n_in,
                                              const float* __restrict__ y_in,
                                              const float* __restrict__ nmax,
                                              float* __restrict__ out) {
    __shared__ __align__(16) unsigned short QsL[32 * 72];
    __shared__ __align__(16) unsigned short QtL[128 * 72];
    __shared__ float rowc[32];
    __shared__ float tqL[128], ytL[128];
    __shared__ float redN[2][32], redD[2][32];

    int tid = threadIdx.x;
    int bh = blockIdx.x >> 6;
    int tile = blockIdx.x & 63;
    int s0 = tile * 32;
    int b = bh >> 3, h = bh & 7;
    int rowbase = (b * 2048) * 512 + h * 64;

    int r = tid >> 3, seg = tid & 7;
    *(uint4*)&QsL[r * 72 + seg * 8] =
        *(const uint4*)&Qh[rowbase + (s0 + r) * 512 + seg * 8];
    float Nv = nmax[bh];
    if (tid < 32) {
        float ns = n_in[bh * 2048 + s0 + tid];
        rowc[tid] = -0.125f * LOG2E * Nv * (2.f * ns - 1.f);
    }
    __syncthreads();

    int lane = tid & 63;
    int w = tid >> 6;
    int rh = w >> 1;                 // row-half (16 rows)
    int cg = w & 1;                  // col-group: 4 col-tiles
    int tt = lane & 15, quad = lane >> 4;
    int arow = rh * 16 + tt;
    bf16x8 a0 = *(const bf16x8*)&QsL[arow * 72 + quad * 8];
    bf16x8 a1 = *(const bf16x8*)&QsL[arow * 72 + quad * 8 + 32];
    float rc[4];
    #pragma unroll
    for (int g = 0; g < 4; ++g) rc[g] = rowc[rh * 16 + quad * 4 + g];
    f32x4 num = {0.f, 0.f, 0.f, 0.f}, den = {0.f, 0.f, 0.f, 0.f};

    for (int t0 = 0; t0 < 2048; t0 += 128) {
        __syncthreads();
        #pragma unroll
        for (int q = 0; q < 4; ++q) {
            int row = (tid >> 3) + q * 32;
            *(uint4*)&QtL[row * 72 + seg * 8] =
                *(const uint4*)&Qh[rowbase + (t0 + row) * 512 + seg * 8];
        }
        if (tid < 128)
            tqL[tid] = -0.125f * LOG2E * n_in[bh * 2048 + t0 + tid];
        else
            ytL[tid - 128] = y_in[bh * 2048 + t0 + tid - 128];
        __syncthreads();

        #pragma unroll
        for (int j = 0; j < 4; ++j) {
            int trow = (cg * 4 + j) * 16 + tt;
            bf16x8 b0 = *(const bf16x8*)&QtL[trow * 72 + quad * 8];
            bf16x8 b1 = *(const bf16x8*)&QtL[trow * 72 + quad * 8 + 32];
            f32x4 dot = {0.f, 0.f, 0.f, 0.f};
            dot = __builtin_amdgcn_mfma_f32_16x16x32_bf16(a0, b0, dot, 0, 0, 0);
            dot = __builtin_amdgcn_mfma_f32_16x16x32_bf16(a1, b1, dot, 0, 0, 0);
            float tqv = tqL[trow], yv = ytL[trow];
            #pragma unroll
            for (int g = 0; g < 4; ++g) {
                float arg = fmaf(0.25f * LOG2E, dot[g], rc[g] + tqv);
                float e = EXP2F(arg);
                num[g] = fmaf(e, yv, num[g]);
                den[g] += e;
            }
        }
    }

    #pragma unroll
    for (int off = 1; off <= 8; off <<= 1) {
        #pragma unroll
        for (int g = 0; g < 4; ++g) {
            num[g] += __shfl_xor(num[g], off);
            den[g] += __shfl_xor(den[g], off);
        }
    }
    if (tt == 0) {
        #pragma unroll
        for (int g = 0; g < 4; ++g) {
            redN[cg][rh * 16 + quad * 4 + g] = num[g];
            redD[cg][rh * 16 + quad * 4 + g] = den[g];
        }
    }
    __syncthreads();
    if (tid < 32) {
        float xn = redN[0][tid] + redN[1][tid];
        float xd = redD[0][tid] + redD[1][tid];
        float x = xn / xd;
        out[bh * 2048 + s0 + tid] = 1.0f / (1.0f + EXP2F(-x * LOG2E));
    }
}

extern "C" void kernel_launch(void* const* d_in, const int* in_sizes, int n_in,
                              void* d_out, int out_size, void* d_ws, size_t ws_size,
                              hipStream_t stream) {
    const float* X  = (const float*)d_in[0];
    const float* Wq = (const float*)d_in[1];
    const float* Wv = (const float*)d_in[2];
    float* out = (float*)d_out;
    float* ws = (float*)d_ws;

    float* t_ws    = ws;                 // 512
    float* u_ws    = ws + 512;           // 4096
    float* n_ws    = ws + 4608;          // 32768
    float* y_ws    = ws + 37376;         // 32768
    float* nmax_ws = ws + 70144;         // 16
    unsigned short* Qh_ws  = (unsigned short*)(ws + 70160);      // 2M bf16
    unsigned short* Xh_ws  = Qh_ws + 2097152;                    // 2M bf16
    unsigned short* Wqt_ws = Xh_ws + 2097152;                    // 256K bf16

    prep_k<<<1288, 256, 0, stream>>>(X, Wq, Wv, Xh_ws, Wqt_ws, t_ws);
    u2_k<<<16, 256, 0, stream>>>(Wq, t_ws, u_ws);
    gemm_k<<<dim3(8, 64), 256, 0, stream>>>(Xh_ws, Wqt_ws, Qh_ws);
    ny_k<<<1024, 256, 0, stream>>>(X, Qh_ws, u_ws, n_ws, y_ws);
    nmax_k<<<16, 256, 0, stream>>>(n_ws, nmax_ws);
    attn_k<<<1024, 256, 0, stream>>>(Qh_ws, n_ws, y_ws, nmax_ws, out);
}